// Round 1
// baseline (689.617 us; speedup 1.0000x reference)
//
#include <hip/hip_runtime.h>

typedef unsigned short u16;
typedef unsigned int u32;
typedef __attribute__((ext_vector_type(8))) short short8;
typedef __attribute__((ext_vector_type(4))) float floatx4;

__device__ __forceinline__ float bf2f(u16 x) {
    union { u32 u; float f; } c; c.u = ((u32)x) << 16; return c.f;
}
__device__ __forceinline__ u16 f2bf(float f) {
    union { float f; u32 u; } c; c.f = f;
    return (u16)((c.u + 0x7FFFu + ((c.u >> 16) & 1u)) >> 16);
}

// async global->LDS, 16B per lane. LDS dest = wave-uniform base + lane*16.
#define GLD_LDS(g, l) __builtin_amdgcn_global_load_lds( \
    (const __attribute__((address_space(1))) u32*)(g),  \
    (__attribute__((address_space(3))) u32*)(l), 16, 0, 0)

// ---------------- f32 -> bf16 convert (optional fused relu) ----------------

__global__ void cvt_kernel(const float* __restrict__ src, u16* __restrict__ dst,
                           int n8, int do_relu) {
    int i = blockIdx.x * 256 + threadIdx.x;
    if (i >= n8) return;
    float4 a = ((const float4*)src)[2 * i];
    float4 b = ((const float4*)src)[2 * i + 1];
    float v[8] = {a.x, a.y, a.z, a.w, b.x, b.y, b.z, b.w};
    short8 o;
#pragma unroll
    for (int j = 0; j < 8; j++) {
        float x = v[j];
        if (do_relu) x = fmaxf(x, 0.f);
        o[j] = (short)f2bf(x);
    }
    ((short8*)dst)[i] = o;
}

// ---------------- stats / gates (pure f32) ----------------

// column mean over sequence: x [B,N,1024] f32 -> out [B*1024] f32 (pre-zeroed)
__global__ void mean_kernel(const float* __restrict__ x, float* __restrict__ out,
                            int N, int chunk) {
    int idx = blockIdx.x * 256 + threadIdx.x;   // (b,d) in [0, 8192)
    int b = idx >> 10, d = idx & 1023;
    int nlo = blockIdx.y * chunk;
    const float* p = x + (size_t)b * N * 1024 + (size_t)nlo * 1024 + d;
    float s = 0.f;
    for (int n = 0; n < chunk; n++) s += p[(size_t)n * 1024];
    atomicAdd(out + idx, s * (1.0f / (float)N));
}

// gate[b,n] = 1 + sigmoid( relu(mean[b,:]) . Wg[n,:] + bg[n] ), one wave/output
__global__ __launch_bounds__(256) void gate_kernel(const float* __restrict__ mean,
                                                   const float* __restrict__ Wg,
                                                   const float* __restrict__ bg,
                                                   float* __restrict__ gout) {
    int gw = blockIdx.x * 4 + (threadIdx.x >> 6);   // [0, 8192)
    int lane = threadIdx.x & 63;
    int b = gw >> 10, n = gw & 1023;
    const float* wr = Wg + (size_t)n * 1024;
    const float* mr = mean + b * 1024;
    float acc = 0.f;
    for (int k = lane; k < 1024; k += 64)
        acc += fmaxf(mr[k], 0.f) * wr[k];
#pragma unroll
    for (int m = 1; m < 64; m <<= 1) acc += __shfl_xor(acc, m, 64);
    if (lane == 0) {
        float xg = acc + bg[n];
        gout[gw] = 1.f + 1.f / (1.f + __expf(-xg));
    }
}

// residual: c_bf16[i] = a_f32[i] + b_bf16[i]
__global__ void add_kernel(const float* __restrict__ a, const u16* __restrict__ b,
                           u16* __restrict__ c, int n) {
    int i = blockIdx.x * 256 + threadIdx.x;
    if (i >= n) return;
    c[i] = f2bf(a[i] + bf2f(b[i]));
}

// ---------------- GEMM: C[M,N] = A[M,K] . W[N,K]^T + bias, optional (1+gate) ----------------
// A, W bf16 (pre-converted in ws). 128x128 tile, BK=32, 4 waves (2x2), each
// wave 4x4 MFMA 16x16x32. m97-style GLD_LDS staging (value-validated r2==r3).
// Output: bf16 (Ch) or f32 (Cf), exactly one non-null.

__global__ __launch_bounds__(256) void gemm_bt_kernel(
    const u16* __restrict__ A, const u16* __restrict__ W,
    const float* __restrict__ bias, const float* __restrict__ gate,
    u16* __restrict__ Ch, float* __restrict__ Cf,
    int M, int N, int K, int seq, int gateN)
{
    __shared__ u16 As[128 * 32];   // [m][k] row-major, 8 KB
    __shared__ u16 Bs[128 * 32];   // [n][k] row-major, 8 KB

    const int tid = threadIdx.x;
    const int wave = tid >> 6, lane = tid & 63, quad = lane >> 4, l15 = lane & 15;
    const int m0 = blockIdx.y * 128, n0 = blockIdx.x * 128;
    const int wm = (wave >> 1) * 64, wn = (wave & 1) * 64;

    floatx4 acc[4][4] = {};

    // staging map: round r covers tile bytes [r*4096 + wave*1024 + lane*16, +16)
    const int e0 = (wave * 1024 + lane * 16) >> 1;       // elements, round 0
    const int sr0 = e0 >> 5, sc0 = e0 & 31;
    const int e1 = e0 + 2048;                            // round 1
    const int sr1 = e1 >> 5, sc1 = e1 & 31;
    const size_t aoff0 = (size_t)(m0 + sr0) * K + sc0;
    const size_t aoff1 = (size_t)(m0 + sr1) * K + sc1;
    const size_t boff0 = (size_t)(n0 + sr0) * K + sc0;
    const size_t boff1 = (size_t)(n0 + sr1) * K + sc1;

    for (int k0 = 0; k0 < K; k0 += 32) {
        GLD_LDS(A + aoff0 + k0, As + wave * 512);
        GLD_LDS(A + aoff1 + k0, As + 2048 + wave * 512);
        GLD_LDS(W + boff0 + k0, Bs + wave * 512);
        GLD_LDS(W + boff1 + k0, Bs + 2048 + wave * 512);
        __syncthreads();

        short8 af[4], bfr[4];
#pragma unroll
        for (int i = 0; i < 4; i++) {
            af[i]  = *(const short8*)(As + (wm + i * 16 + l15) * 32 + quad * 8);
            bfr[i] = *(const short8*)(Bs + (wn + i * 16 + l15) * 32 + quad * 8);
        }
#pragma unroll
        for (int mi = 0; mi < 4; mi++)
#pragma unroll
            for (int ni = 0; ni < 4; ni++)
                acc[mi][ni] = __builtin_amdgcn_mfma_f32_16x16x32_bf16(af[mi], bfr[ni], acc[mi][ni], 0, 0, 0);
        __syncthreads();
    }

    const int b = m0 / seq;
#pragma unroll
    for (int ni = 0; ni < 4; ni++) {
        const int ncol = n0 + wn + ni * 16 + l15;
        const float bsv = bias[ncol];
        float g = 1.f;
        if (gate != nullptr && ncol < gateN) g = gate[b * 1024 + (ncol & 1023)];
#pragma unroll
        for (int mi = 0; mi < 4; mi++) {
            const int row = m0 + wm + mi * 16 + quad * 4;
#pragma unroll
            for (int r = 0; r < 4; r++) {
                float val = (acc[mi][ni][r] + bsv) * g;
                size_t idx = (size_t)(row + r) * N + ncol;
                if (Cf) Cf[idx] = val; else Ch[idx] = f2bf(val);
            }
        }
    }
}

// ---------------- fused flash attention ----------------
// T: [B, N, 3072] bf16 gated trans (k | q | v thirds, 8 heads x 128 each).
// U: [B, N, 1024] bf16 update. Block = (128 q-rows, b*8+h). 4 waves x 32 rows.
// KVBLK=64. All LDS tiles XOR-swizzled for ~2-way (free) bank access:
//   Ks [kv][128]: slot s (16B) stored at s^(kv&15); staged via GLD_LDS with
//                 PRE-SWIZZLED GLOBAL SOURCE (linear LDS dest, rule 21).
//   Vs [d][kv]:   slot s (8 kv) stored at s^(d&7); manual transpose-pack,
//                 thread map kvp=tid&31 / d8=tid>>5 -> 32 distinct write banks.
//   Ps [q][kv]:   slot s stored at s^(row&7), same XOR write+read (involution).

__global__ __launch_bounds__(256) void attn_kernel(
    const u16* __restrict__ T, u16* __restrict__ U, int N)
{
    __shared__ __align__(16) u16 Ks[64 * 128];     // 16 KB, swizzled [kv][d]
    __shared__ __align__(16) u16 Vs[128 * 64];     // 16 KB, swizzled [d][kv]
    __shared__ __align__(16) u16 Ps[4][32 * 64];   // 16 KB, per-wave 32x64 P

    const int tid = threadIdx.x;
    const int wave = tid >> 6, lane = tid & 63, quad = lane >> 4, l15 = lane & 15;
    const int qb = blockIdx.x;
    const int b = blockIdx.y >> 3, h = blockIdx.y & 7;

    const size_t base = (size_t)b * N * 3072;
    const int kcol = h * 128, qcol = 1024 + h * 128, vcol = 2048 + h * 128;

    // Q fragments held in registers for the whole pass
    short8 qf[2][4];
    const int qrow0 = qb * 128 + wave * 32;
#pragma unroll
    for (int mi = 0; mi < 2; mi++)
#pragma unroll
        for (int c = 0; c < 4; c++)
            qf[mi][c] = *(const short8*)(T + base + (size_t)(qrow0 + mi * 16 + l15) * 3072
                                           + qcol + c * 32 + quad * 8);

    floatx4 o[2][8] = {};
    float mrow[2][4], lrow[2][4];
#pragma unroll
    for (int mi = 0; mi < 2; mi++)
#pragma unroll
        for (int r = 0; r < 4; r++) { mrow[mi][r] = -1e30f; lrow[mi][r] = 0.f; }

    const float scale = 0.08838834764831845f;  // 1/sqrt(128)

    // K staging map: round r covers Ks bytes [r*4096 + wave*1024 + lane*16, +16).
    // LDS byte ob holds K[kv = ob>>8][d = (((ob>>4)&15) ^ (kv&15))*8 .. +8)
    int kst_kv[4], kst_d[4];
#pragma unroll
    for (int r = 0; r < 4; r++) {
        int ob = r * 4096 + wave * 1024 + lane * 16;
        int kv = ob >> 8;
        kst_kv[r] = kv;
        kst_d[r] = ((((ob >> 4) & 15) ^ (kv & 15)) << 3);
    }
    // V staging map: 32 distinct banks per store across a wave
    const int vkv = (tid & 31) * 2;     // kv pair base
    const int vd8 = tid >> 5;           // [0,8)

    for (int kt = 0; kt < N; kt += 64) {
        // ---- stage K via async DMA (pre-swizzled source) ----
#pragma unroll
        for (int r = 0; r < 4; r++)
            GLD_LDS(T + base + (size_t)(kt + kst_kv[r]) * 3072 + kcol + kst_d[r],
                    Ks + r * 2048 + wave * 512);
        // ---- stage V transposed+swizzled (overlaps K DMA) ----
#pragma unroll
        for (int pp = 0; pp < 2; pp++) {
            const int dbase = (vd8 + 8 * pp) * 8;
            const u16* vp0 = T + base + (size_t)(kt + vkv) * 3072 + vcol + dbase;
            short8 v0 = *(const short8*)vp0;
            short8 v1 = *(const short8*)(vp0 + 3072);
#pragma unroll
            for (int j = 0; j < 8; j++) {
                u32 wv = ((u32)(u16)v0[j]) | (((u32)(u16)v1[j]) << 16);
                *(u32*)((char*)Vs + (size_t)(dbase + j) * 128
                        + ((((vkv >> 3) ^ j)) << 4) + ((vkv * 2) & 15)) = wv;
            }
        }
        __syncthreads();

        // ---- QK^T: 32 MFMA, swizzled conflict-free K reads ----
        float p[2][4][4];
#pragma unroll
        for (int ni = 0; ni < 4; ni++) {
            short8 kf[4];
#pragma unroll
            for (int c = 0; c < 4; c++)
                kf[c] = *(const short8*)(Ks + (ni * 16 + l15) * 128
                                            + (((c * 4 + quad) ^ l15) << 3));
#pragma unroll
            for (int mi = 0; mi < 2; mi++) {
                floatx4 s = {0.f, 0.f, 0.f, 0.f};
#pragma unroll
                for (int c = 0; c < 4; c++)
                    s = __builtin_amdgcn_mfma_f32_16x16x32_bf16(qf[mi][c], kf[c], s, 0, 0, 0);
#pragma unroll
                for (int r = 0; r < 4; r++) p[mi][ni][r] = s[r] * scale;
            }
        }

        // ---- online softmax (one pass per 64 kv) ----
#pragma unroll
        for (int mi = 0; mi < 2; mi++)
#pragma unroll
            for (int r = 0; r < 4; r++) {
                float tm = fmaxf(fmaxf(p[mi][0][r], p[mi][1][r]),
                                 fmaxf(p[mi][2][r], p[mi][3][r]));
#pragma unroll
                for (int msk = 1; msk < 16; msk <<= 1) tm = fmaxf(tm, __shfl_xor(tm, msk, 64));
                float mnew = fmaxf(mrow[mi][r], tm);
                float alpha = __expf(mrow[mi][r] - mnew);
                mrow[mi][r] = mnew;
                float ps = 0.f;
#pragma unroll
                for (int ni = 0; ni < 4; ni++) {
                    float pe = __expf(p[mi][ni][r] - mnew);
                    p[mi][ni][r] = pe;
                    ps += pe;
                }
#pragma unroll
                for (int msk = 1; msk < 16; msk <<= 1) ps += __shfl_xor(ps, msk, 64);
                lrow[mi][r] = lrow[mi][r] * alpha + ps;
#pragma unroll
                for (int nt = 0; nt < 8; nt++) o[mi][nt][r] *= alpha;
            }

        // ---- P -> LDS (swizzled), per-wave buffer ----
#pragma unroll
        for (int mi = 0; mi < 2; mi++)
#pragma unroll
            for (int ni = 0; ni < 4; ni++)
#pragma unroll
                for (int r = 0; r < 4; r++) {
                    const int row = mi * 16 + quad * 4 + r;
                    const int col = ni * 16 + l15;
                    Ps[wave][row * 64 + ((((col >> 3) ^ (row & 7))) << 3) + (col & 7)]
                        = f2bf(p[mi][ni][r]);
                }

        short8 pf[2][2];
#pragma unroll
        for (int mi = 0; mi < 2; mi++)
#pragma unroll
            for (int kc = 0; kc < 2; kc++)
                pf[mi][kc] = *(const short8*)(&Ps[wave][(mi * 16 + l15) * 64
                                + (((kc * 4 + quad) ^ (l15 & 7)) << 3)]);

        // ---- PV: 32 MFMA, swizzled conflict-free V reads ----
#pragma unroll
        for (int nt = 0; nt < 8; nt++) {
#pragma unroll
            for (int kc = 0; kc < 2; kc++) {
                short8 vf = *(const short8*)(Vs + (nt * 16 + l15) * 64
                                + (((kc * 4 + quad) ^ (l15 & 7)) << 3));
#pragma unroll
                for (int mi = 0; mi < 2; mi++)
                    o[mi][nt] = __builtin_amdgcn_mfma_f32_16x16x32_bf16(pf[mi][kc], vf, o[mi][nt], 0, 0, 0);
            }
        }
        __syncthreads();
    }

    const size_t ub = (size_t)b * N * 1024;
#pragma unroll
    for (int mi = 0; mi < 2; mi++)
#pragma unroll
        for (int r = 0; r < 4; r++) {
            float inv = 1.f / lrow[mi][r];
            const size_t row = qb * 128 + wave * 32 + mi * 16 + quad * 4 + r;
#pragma unroll
            for (int nt = 0; nt < 8; nt++)
                U[ub + row * 1024 + h * 128 + nt * 16 + l15] = f2bf(o[mi][nt][r] * inv);
        }
}

// ---------------- launch ----------------
// Inputs f32, outputs f32 (both per reference dtypes). ws peak = 80.1 MB:
// stats 128 KB | weights 8 MB @1MB | activations 16 MB @16MB | trans 48 MB @32MB.
// q phase then v phase reuse the same regions sequentially.

extern "C" void kernel_launch(void* const* d_in, const int* in_sizes, int n_in,
                              void* d_out, int out_size, void* d_ws, size_t ws_size,
                              hipStream_t stream) {
    (void)in_sizes; (void)n_in; (void)out_size; (void)ws_size;
    const float* v   = (const float*)d_in[0];
    const float* q   = (const float*)d_in[1];
    const float* Wg_v4q = (const float*)d_in[2];
    const float* bg_v4q = (const float*)d_in[3];
    const float* Wg_q4v = (const float*)d_in[4];
    const float* bg_q4v = (const float*)d_in[5];
    const float* Wv  = (const float*)d_in[6];
    const float* bv  = (const float*)d_in[7];
    const float* Wq  = (const float*)d_in[8];
    const float* bq  = (const float*)d_in[9];
    const float* Wvo = (const float*)d_in[10];
    const float* bvo = (const float*)d_in[11];
    const float* Wqo = (const float*)d_in[12];
    const float* bqo = (const float*)d_in[13];
    float* out = (float*)d_out;                     // [v: 8388608][q: 4194304] f32

    char* w = (char*)d_ws;
    float* vmean = (float*)(w + 0);                 // 32 KB
    float* qmean = (float*)(w + 32768);
    float* gv4q  = (float*)(w + 65536);
    float* gq4v  = (float*)(w + 98304);
    u16* cWt  = (u16*)(w + (1 << 20));              // 6 MB (trans weight bf16)
    u16* cWo  = (u16*)(w + (1 << 20) + 6291456);    // 2 MB (proj weight bf16)
    u16* aReg = (u16*)(w + (16 << 20));             // 16 MB (relu acts / updates)
    u16* tReg = (u16*)(w + (32 << 20));             // 48 MB (trans / residual sum)

    // stats + gates
    hipMemsetAsync(vmean, 0, 65536, stream);        // covers vmean + qmean
    mean_kernel<<<dim3(32, 8), 256, 0, stream>>>(v, vmean, 1024, 128);
    mean_kernel<<<dim3(32, 8), 256, 0, stream>>>(q, qmean, 512, 64);
    gate_kernel<<<2048, 256, 0, stream>>>(vmean, Wg_v4q, bg_v4q, gv4q);  // for q pipeline
    gate_kernel<<<2048, 256, 0, stream>>>(qmean, Wg_q4v, bg_q4v, gq4v);  // for v pipeline

    // ---- q phase ----
    u16* crq  = aReg;                               // bf16 relu(q), 8 MB
    u16* qt   = tReg;                               // [8,512,3072] bf16, 24 MB
    u16* qupd = aReg;                               // reuses crq after trans GEMM
    u16* qsum = tReg;                               // reuses qt after attention
    cvt_kernel<<<2048, 256, 0, stream>>>(q, crq, 524288, 1);
    cvt_kernel<<<1536, 256, 0, stream>>>(Wq, cWt, 393216, 0);
    cvt_kernel<<<512, 256, 0, stream>>>(Wqo, cWo, 131072, 0);
    gemm_bt_kernel<<<dim3(24, 32), 256, 0, stream>>>(crq, cWt, bq, gv4q, qt, nullptr,
                                                     4096, 3072, 1024, 512, 2048);
    attn_kernel<<<dim3(4, 64), 256, 0, stream>>>(qt, qupd, 512);
    add_kernel<<<16384, 256, 0, stream>>>(q, qupd, qsum, 4194304);
    gemm_bt_kernel<<<dim3(8, 32), 256, 0, stream>>>(qsum, cWo, bqo, nullptr, nullptr,
                                                    out + 8388608, 4096, 1024, 1024, 512, 0);

    // ---- v phase ----
    u16* crv  = aReg;                               // bf16 relu(v), 16 MB
    u16* vt   = tReg;                               // [8,1024,3072] bf16, 48 MB
    u16* vupd = aReg;
    u16* vsum = tReg;
    cvt_kernel<<<4096, 256, 0, stream>>>(v, crv, 1048576, 1);
    cvt_kernel<<<1536, 256, 0, stream>>>(Wv, cWt, 393216, 0);
    cvt_kernel<<<512, 256, 0, stream>>>(Wvo, cWo, 131072, 0);
    gemm_bt_kernel<<<dim3(24, 64), 256, 0, stream>>>(crv, cWt, bv, gq4v, vt, nullptr,
                                                     8192, 3072, 1024, 1024, 2048);
    attn_kernel<<<dim3(8, 64), 256, 0, stream>>>(vt, vupd, 1024);
    add_kernel<<<32768, 256, 0, stream>>>(v, vupd, vsum, 8388608);
    gemm_bt_kernel<<<dim3(8, 64), 256, 0, stream>>>(vsum, cWo, bvo, nullptr, nullptr,
                                                    out, 8192, 1024, 1024, 1024, 0);
}

// Round 2
// 640.776 us; speedup vs baseline: 1.0762x; 1.0762x over previous
//
#include <hip/hip_runtime.h>

typedef unsigned short u16;
typedef unsigned int u32;
typedef __attribute__((ext_vector_type(8))) short short8;
typedef __attribute__((ext_vector_type(4))) float floatx4;

__device__ __forceinline__ float bf2f(u16 x) {
    union { u32 u; float f; } c; c.u = ((u32)x) << 16; return c.f;
}
__device__ __forceinline__ u16 f2bf(float f) {
    union { float f; u32 u; } c; c.f = f;
    return (u16)((c.u + 0x7FFFu + ((c.u >> 16) & 1u)) >> 16);
}

// async global->LDS, 16B per lane. LDS dest = wave-uniform base + lane*16.
#define GLD_LDS(g, l) __builtin_amdgcn_global_load_lds( \
    (const __attribute__((address_space(1))) u32*)(g),  \
    (__attribute__((address_space(3))) u32*)(l), 16, 0, 0)

// ---------------- f32 -> bf16 convert (optional fused relu) ----------------

__global__ void cvt_kernel(const float* __restrict__ src, u16* __restrict__ dst,
                           int n8, int do_relu) {
    int i = blockIdx.x * 256 + threadIdx.x;
    if (i >= n8) return;
    float4 a = ((const float4*)src)[2 * i];
    float4 b = ((const float4*)src)[2 * i + 1];
    float v[8] = {a.x, a.y, a.z, a.w, b.x, b.y, b.z, b.w};
    short8 o;
#pragma unroll
    for (int j = 0; j < 8; j++) {
        float x = v[j];
        if (do_relu) x = fmaxf(x, 0.f);
        o[j] = (short)f2bf(x);
    }
    ((short8*)dst)[i] = o;
}

// ---------------- stats / gates (pure f32) ----------------

// column mean over sequence: x [B,N,1024] f32 -> out [B*1024] f32 (pre-zeroed)
__global__ void mean_kernel(const float* __restrict__ x, float* __restrict__ out,
                            int N, int chunk) {
    int idx = blockIdx.x * 256 + threadIdx.x;   // (b,d) in [0, 8192)
    int b = idx >> 10, d = idx & 1023;
    int nlo = blockIdx.y * chunk;
    const float* p = x + (size_t)b * N * 1024 + (size_t)nlo * 1024 + d;
    float s = 0.f;
    for (int n = 0; n < chunk; n++) s += p[(size_t)n * 1024];
    atomicAdd(out + idx, s * (1.0f / (float)N));
}

// gate[b,n] = 1 + sigmoid( relu(mean[b,:]) . Wg[n,:] + bg[n] ), one wave/output
__global__ __launch_bounds__(256) void gate_kernel(const float* __restrict__ mean,
                                                   const float* __restrict__ Wg,
                                                   const float* __restrict__ bg,
                                                   float* __restrict__ gout) {
    int gw = blockIdx.x * 4 + (threadIdx.x >> 6);   // [0, 8192)
    int lane = threadIdx.x & 63;
    int b = gw >> 10, n = gw & 1023;
    const float* wr = Wg + (size_t)n * 1024;
    const float* mr = mean + b * 1024;
    float acc = 0.f;
    for (int k = lane; k < 1024; k += 64)
        acc += fmaxf(mr[k], 0.f) * wr[k];
#pragma unroll
    for (int m = 1; m < 64; m <<= 1) acc += __shfl_xor(acc, m, 64);
    if (lane == 0) {
        float xg = acc + bg[n];
        gout[gw] = 1.f + 1.f / (1.f + __expf(-xg));
    }
}

// residual: c_bf16[i] = a_f32[i] + b_bf16[i]
__global__ void add_kernel(const float* __restrict__ a, const u16* __restrict__ b,
                           u16* __restrict__ c, int n) {
    int i = blockIdx.x * 256 + threadIdx.x;
    if (i >= n) return;
    c[i] = f2bf(a[i] + bf2f(b[i]));
}

// ---------------- GEMM: C[M,N] = A[M,K] . W[N,K]^T + bias, optional (1+gate) ----------------
// A, W bf16 (pre-converted in ws). 128x128 tile, BK=32, 4 waves (2x2), each
// wave 4x4 MFMA 16x16x32. m97-style GLD_LDS staging (value-validated r2==r3).
// Output: bf16 (Ch) or f32 (Cf), exactly one non-null.

__global__ __launch_bounds__(256) void gemm_bt_kernel(
    const u16* __restrict__ A, const u16* __restrict__ W,
    const float* __restrict__ bias, const float* __restrict__ gate,
    u16* __restrict__ Ch, float* __restrict__ Cf,
    int M, int N, int K, int seq, int gateN)
{
    __shared__ u16 As[128 * 32];   // [m][k] row-major, 8 KB
    __shared__ u16 Bs[128 * 32];   // [n][k] row-major, 8 KB

    const int tid = threadIdx.x;
    const int wave = tid >> 6, lane = tid & 63, quad = lane >> 4, l15 = lane & 15;
    const int m0 = blockIdx.y * 128, n0 = blockIdx.x * 128;
    const int wm = (wave >> 1) * 64, wn = (wave & 1) * 64;

    floatx4 acc[4][4] = {};

    // staging map: round r covers tile bytes [r*4096 + wave*1024 + lane*16, +16)
    const int e0 = (wave * 1024 + lane * 16) >> 1;       // elements, round 0
    const int sr0 = e0 >> 5, sc0 = e0 & 31;
    const int e1 = e0 + 2048;                            // round 1
    const int sr1 = e1 >> 5, sc1 = e1 & 31;
    const size_t aoff0 = (size_t)(m0 + sr0) * K + sc0;
    const size_t aoff1 = (size_t)(m0 + sr1) * K + sc1;
    const size_t boff0 = (size_t)(n0 + sr0) * K + sc0;
    const size_t boff1 = (size_t)(n0 + sr1) * K + sc1;

    for (int k0 = 0; k0 < K; k0 += 32) {
        GLD_LDS(A + aoff0 + k0, As + wave * 512);
        GLD_LDS(A + aoff1 + k0, As + 2048 + wave * 512);
        GLD_LDS(W + boff0 + k0, Bs + wave * 512);
        GLD_LDS(W + boff1 + k0, Bs + 2048 + wave * 512);
        __syncthreads();

        short8 af[4], bfr[4];
#pragma unroll
        for (int i = 0; i < 4; i++) {
            af[i]  = *(const short8*)(As + (wm + i * 16 + l15) * 32 + quad * 8);
            bfr[i] = *(const short8*)(Bs + (wn + i * 16 + l15) * 32 + quad * 8);
        }
#pragma unroll
        for (int mi = 0; mi < 4; mi++)
#pragma unroll
            for (int ni = 0; ni < 4; ni++)
                acc[mi][ni] = __builtin_amdgcn_mfma_f32_16x16x32_bf16(af[mi], bfr[ni], acc[mi][ni], 0, 0, 0);
        __syncthreads();
    }

    const int b = m0 / seq;
#pragma unroll
    for (int ni = 0; ni < 4; ni++) {
        const int ncol = n0 + wn + ni * 16 + l15;
        const float bsv = bias[ncol];
        float g = 1.f;
        if (gate != nullptr && ncol < gateN) g = gate[b * 1024 + (ncol & 1023)];
#pragma unroll
        for (int mi = 0; mi < 4; mi++) {
            const int row = m0 + wm + mi * 16 + quad * 4;
#pragma unroll
            for (int r = 0; r < 4; r++) {
                float val = (acc[mi][ni][r] + bsv) * g;
                size_t idx = (size_t)(row + r) * N + ncol;
                if (Cf) Cf[idx] = val; else Ch[idx] = f2bf(val);
            }
        }
    }
}

// ---------------- fused flash attention ----------------
// T: [B, N, 3072] bf16 gated trans (k | q | v thirds, 8 heads x 128 each).
// U: [B, N, 1024] bf16 update. Block = (128 q-rows, b*8+h). 4 waves x 32 rows.
// KVBLK=64, DOUBLE-BUFFERED K/V (T3 2-phase) + issue-early/write-late V
// staging (T14). All LDS tiles XOR-swizzled (validated r1: bank conflicts = 0):
//   Ks [kv][128]: slot s (16B) stored at s^(kv&15); staged via GLD_LDS with
//                 PRE-SWIZZLED GLOBAL SOURCE (linear LDS dest, rule 21).
//   Vs [d][kv]:   slot s (8 kv) stored at s^(d&7); manual transpose-pack.
//   Ps [q][kv]:   slot s stored at s^(row&7), same XOR write+read.

__global__ __launch_bounds__(256) void attn_kernel(
    const u16* __restrict__ T, u16* __restrict__ U, int N)
{
    __shared__ __align__(16) u16 Ks[2][64 * 128];  // 2 x 16 KB, swizzled [kv][d]
    __shared__ __align__(16) u16 Vs[2][128 * 64];  // 2 x 16 KB, swizzled [d][kv]
    __shared__ __align__(16) u16 Ps[4][32 * 64];   // 16 KB, per-wave 32x64 P

    const int tid = threadIdx.x;
    const int wave = tid >> 6, lane = tid & 63, quad = lane >> 4, l15 = lane & 15;
    const int qb = blockIdx.x;
    const int b = blockIdx.y >> 3, h = blockIdx.y & 7;

    const size_t base = (size_t)b * N * 3072;
    const int kcol = h * 128, qcol = 1024 + h * 128, vcol = 2048 + h * 128;

    // Q fragments held in registers for the whole pass
    short8 qf[2][4];
    const int qrow0 = qb * 128 + wave * 32;
#pragma unroll
    for (int mi = 0; mi < 2; mi++)
#pragma unroll
        for (int c = 0; c < 4; c++)
            qf[mi][c] = *(const short8*)(T + base + (size_t)(qrow0 + mi * 16 + l15) * 3072
                                           + qcol + c * 32 + quad * 8);

    floatx4 o[2][8] = {};
    float mrow[2][4], lrow[2][4];
#pragma unroll
    for (int mi = 0; mi < 2; mi++)
#pragma unroll
        for (int r = 0; r < 4; r++) { mrow[mi][r] = -1e30f; lrow[mi][r] = 0.f; }

    const float scale = 0.08838834764831845f;  // 1/sqrt(128)

    // K staging map: round r covers Ks bytes [r*4096 + wave*1024 + lane*16, +16).
    // LDS byte ob holds K[kv = ob>>8][d = (((ob>>4)&15) ^ (kv&15))*8 .. +8)
    int kst_kv[4], kst_d[4];
#pragma unroll
    for (int r = 0; r < 4; r++) {
        int ob = r * 4096 + wave * 1024 + lane * 16;
        int kv = ob >> 8;
        kst_kv[r] = kv;
        kst_d[r] = ((((ob >> 4) & 15) ^ (kv & 15)) << 3);
    }
    // V staging map: 32 distinct banks per store across a wave
    const int vkv = (tid & 31) * 2;     // kv pair base
    const int vd8 = tid >> 5;           // [0,8)

    // ---- prologue: stage tile 0 ----
    short8 vr0[2], vr1[2];
#pragma unroll
    for (int r = 0; r < 4; r++)
        GLD_LDS(T + base + (size_t)kst_kv[r] * 3072 + kcol + kst_d[r],
                Ks[0] + r * 2048 + wave * 512);
#pragma unroll
    for (int pp = 0; pp < 2; pp++) {
        const u16* vp0 = T + base + (size_t)vkv * 3072 + vcol + (vd8 + 8 * pp) * 8;
        vr0[pp] = *(const short8*)vp0;
        vr1[pp] = *(const short8*)(vp0 + 3072);
    }
#pragma unroll
    for (int pp = 0; pp < 2; pp++) {
        const int dbase = (vd8 + 8 * pp) * 8;
#pragma unroll
        for (int j = 0; j < 8; j++) {
            u32 wv = ((u32)(u16)vr0[pp][j]) | (((u32)(u16)vr1[pp][j]) << 16);
            *(u32*)((char*)Vs[0] + (size_t)(dbase + j) * 128
                    + ((((vkv >> 3) ^ j)) << 4) + ((vkv * 2) & 15)) = wv;
        }
    }
    __syncthreads();

    int cur = 0;
    for (int kt = 0; kt < N; kt += 64) {
        const int nxt = cur ^ 1;
        const bool more = (kt + 64) < N;

        // ---- issue next tile's staging EARLY (hides under compute) ----
        if (more) {
#pragma unroll
            for (int r = 0; r < 4; r++)
                GLD_LDS(T + base + (size_t)(kt + 64 + kst_kv[r]) * 3072 + kcol + kst_d[r],
                        Ks[nxt] + r * 2048 + wave * 512);
#pragma unroll
            for (int pp = 0; pp < 2; pp++) {
                const u16* vp0 = T + base + (size_t)(kt + 64 + vkv) * 3072 + vcol + (vd8 + 8 * pp) * 8;
                vr0[pp] = *(const short8*)vp0;
                vr1[pp] = *(const short8*)(vp0 + 3072);
            }
        }

        // ---- QK^T: 32 MFMA, swizzled conflict-free K reads ----
        float p[2][4][4];
        __builtin_amdgcn_s_setprio(1);
#pragma unroll
        for (int ni = 0; ni < 4; ni++) {
            short8 kf[4];
#pragma unroll
            for (int c = 0; c < 4; c++)
                kf[c] = *(const short8*)(Ks[cur] + (ni * 16 + l15) * 128
                                            + (((c * 4 + quad) ^ l15) << 3));
#pragma unroll
            for (int mi = 0; mi < 2; mi++) {
                floatx4 s = {0.f, 0.f, 0.f, 0.f};
#pragma unroll
                for (int c = 0; c < 4; c++)
                    s = __builtin_amdgcn_mfma_f32_16x16x32_bf16(qf[mi][c], kf[c], s, 0, 0, 0);
#pragma unroll
                for (int r = 0; r < 4; r++) p[mi][ni][r] = s[r] * scale;
            }
        }
        __builtin_amdgcn_s_setprio(0);

        // ---- online softmax (one pass per 64 kv) ----
#pragma unroll
        for (int mi = 0; mi < 2; mi++)
#pragma unroll
            for (int r = 0; r < 4; r++) {
                float tm = fmaxf(fmaxf(p[mi][0][r], p[mi][1][r]),
                                 fmaxf(p[mi][2][r], p[mi][3][r]));
#pragma unroll
                for (int msk = 1; msk < 16; msk <<= 1) tm = fmaxf(tm, __shfl_xor(tm, msk, 64));
                float mnew = fmaxf(mrow[mi][r], tm);
                float alpha = __expf(mrow[mi][r] - mnew);
                mrow[mi][r] = mnew;
                float ps = 0.f;
#pragma unroll
                for (int ni = 0; ni < 4; ni++) {
                    float pe = __expf(p[mi][ni][r] - mnew);
                    p[mi][ni][r] = pe;
                    ps += pe;
                }
#pragma unroll
                for (int msk = 1; msk < 16; msk <<= 1) ps += __shfl_xor(ps, msk, 64);
                lrow[mi][r] = lrow[mi][r] * alpha + ps;
#pragma unroll
                for (int nt = 0; nt < 8; nt++) o[mi][nt][r] *= alpha;
            }

        // ---- P -> LDS (swizzled), per-wave buffer ----
#pragma unroll
        for (int mi = 0; mi < 2; mi++)
#pragma unroll
            for (int ni = 0; ni < 4; ni++)
#pragma unroll
                for (int r = 0; r < 4; r++) {
                    const int row = mi * 16 + quad * 4 + r;
                    const int col = ni * 16 + l15;
                    Ps[wave][row * 64 + ((((col >> 3) ^ (row & 7))) << 3) + (col & 7)]
                        = f2bf(p[mi][ni][r]);
                }

        short8 pf[2][2];
#pragma unroll
        for (int mi = 0; mi < 2; mi++)
#pragma unroll
            for (int kc = 0; kc < 2; kc++)
                pf[mi][kc] = *(const short8*)(&Ps[wave][(mi * 16 + l15) * 64
                                + (((kc * 4 + quad) ^ (l15 & 7)) << 3)]);

        // ---- PV: 32 MFMA, swizzled conflict-free V reads ----
        __builtin_amdgcn_s_setprio(1);
#pragma unroll
        for (int nt = 0; nt < 8; nt++) {
#pragma unroll
            for (int kc = 0; kc < 2; kc++) {
                short8 vf = *(const short8*)(Vs[cur] + (nt * 16 + l15) * 64
                                + (((kc * 4 + quad) ^ (l15 & 7)) << 3));
#pragma unroll
                for (int mi = 0; mi < 2; mi++)
                    o[mi][nt] = __builtin_amdgcn_mfma_f32_16x16x32_bf16(pf[mi][kc], vf, o[mi][nt], 0, 0, 0);
            }
        }
        __builtin_amdgcn_s_setprio(0);

        // ---- late V write into next buffer (loads have drained under compute) ----
        if (more) {
#pragma unroll
            for (int pp = 0; pp < 2; pp++) {
                const int dbase = (vd8 + 8 * pp) * 8;
#pragma unroll
                for (int j = 0; j < 8; j++) {
                    u32 wv = ((u32)(u16)vr0[pp][j]) | (((u32)(u16)vr1[pp][j]) << 16);
                    *(u32*)((char*)Vs[nxt] + (size_t)(dbase + j) * 128
                            + ((((vkv >> 3) ^ j)) << 4) + ((vkv * 2) & 15)) = wv;
                }
            }
        }
        __syncthreads();
        cur = nxt;
    }

    const size_t ub = (size_t)b * N * 1024;
#pragma unroll
    for (int mi = 0; mi < 2; mi++)
#pragma unroll
        for (int r = 0; r < 4; r++) {
            float inv = 1.f / lrow[mi][r];
            const size_t row = qb * 128 + wave * 32 + mi * 16 + quad * 4 + r;
#pragma unroll
            for (int nt = 0; nt < 8; nt++)
                U[ub + row * 1024 + h * 128 + nt * 16 + l15] = f2bf(o[mi][nt][r] * inv);
        }
}

// ---------------- launch ----------------
// Inputs f32, outputs f32 (both per reference dtypes). ws peak = 80.1 MB:
// stats 128 KB | weights 8 MB @1MB | activations 16 MB @16MB | trans 48 MB @32MB.
// q phase then v phase reuse the same regions sequentially.

extern "C" void kernel_launch(void* const* d_in, const int* in_sizes, int n_in,
                              void* d_out, int out_size, void* d_ws, size_t ws_size,
                              hipStream_t stream) {
    (void)in_sizes; (void)n_in; (void)out_size; (void)ws_size;
    const float* v   = (const float*)d_in[0];
    const float* q   = (const float*)d_in[1];
    const float* Wg_v4q = (const float*)d_in[2];
    const float* bg_v4q = (const float*)d_in[3];
    const float* Wg_q4v = (const float*)d_in[4];
    const float* bg_q4v = (const float*)d_in[5];
    const float* Wv  = (const float*)d_in[6];
    const float* bv  = (const float*)d_in[7];
    const float* Wq  = (const float*)d_in[8];
    const float* bq  = (const float*)d_in[9];
    const float* Wvo = (const float*)d_in[10];
    const float* bvo = (const float*)d_in[11];
    const float* Wqo = (const float*)d_in[12];
    const float* bqo = (const float*)d_in[13];
    float* out = (float*)d_out;                     // [v: 8388608][q: 4194304] f32

    char* w = (char*)d_ws;
    float* vmean = (float*)(w + 0);                 // 32 KB
    float* qmean = (float*)(w + 32768);
    float* gv4q  = (float*)(w + 65536);
    float* gq4v  = (float*)(w + 98304);
    u16* cWt  = (u16*)(w + (1 << 20));              // 6 MB (trans weight bf16)
    u16* cWo  = (u16*)(w + (1 << 20) + 6291456);    // 2 MB (proj weight bf16)
    u16* aReg = (u16*)(w + (16 << 20));             // 16 MB (relu acts / updates)
    u16* tReg = (u16*)(w + (32 << 20));             // 48 MB (trans / residual sum)

    // stats + gates
    hipMemsetAsync(vmean, 0, 65536, stream);        // covers vmean + qmean
    mean_kernel<<<dim3(32, 8), 256, 0, stream>>>(v, vmean, 1024, 128);
    mean_kernel<<<dim3(32, 8), 256, 0, stream>>>(q, qmean, 512, 64);
    gate_kernel<<<2048, 256, 0, stream>>>(vmean, Wg_v4q, bg_v4q, gv4q);  // for q pipeline
    gate_kernel<<<2048, 256, 0, stream>>>(qmean, Wg_q4v, bg_q4v, gq4v);  // for v pipeline

    // ---- q phase ----
    u16* crq  = aReg;                               // bf16 relu(q), 8 MB
    u16* qt   = tReg;                               // [8,512,3072] bf16, 24 MB
    u16* qupd = aReg;                               // reuses crq after trans GEMM
    u16* qsum = tReg;                               // reuses qt after attention
    cvt_kernel<<<2048, 256, 0, stream>>>(q, crq, 524288, 1);
    cvt_kernel<<<1536, 256, 0, stream>>>(Wq, cWt, 393216, 0);
    cvt_kernel<<<512, 256, 0, stream>>>(Wqo, cWo, 131072, 0);
    gemm_bt_kernel<<<dim3(24, 32), 256, 0, stream>>>(crq, cWt, bq, gv4q, qt, nullptr,
                                                     4096, 3072, 1024, 512, 2048);
    attn_kernel<<<dim3(4, 64), 256, 0, stream>>>(qt, qupd, 512);
    add_kernel<<<16384, 256, 0, stream>>>(q, qupd, qsum, 4194304);
    gemm_bt_kernel<<<dim3(8, 32), 256, 0, stream>>>(qsum, cWo, bqo, nullptr, nullptr,
                                                    out + 8388608, 4096, 1024, 1024, 512, 0);

    // ---- v phase ----
    u16* crv  = aReg;                               // bf16 relu(v), 16 MB
    u16* vt   = tReg;                               // [8,1024,3072] bf16, 48 MB
    u16* vupd = aReg;
    u16* vsum = tReg;
    cvt_kernel<<<4096, 256, 0, stream>>>(v, crv, 1048576, 1);
    cvt_kernel<<<1536, 256, 0, stream>>>(Wv, cWt, 393216, 0);
    cvt_kernel<<<512, 256, 0, stream>>>(Wvo, cWo, 131072, 0);
    gemm_bt_kernel<<<dim3(24, 64), 256, 0, stream>>>(crv, cWt, bv, gq4v, vt, nullptr,
                                                     8192, 3072, 1024, 1024, 2048);
    attn_kernel<<<dim3(8, 64), 256, 0, stream>>>(vt, vupd, 1024);
    add_kernel<<<32768, 256, 0, stream>>>(v, vupd, vsum, 8388608);
    gemm_bt_kernel<<<dim3(8, 64), 256, 0, stream>>>(vsum, cWo, bvo, nullptr, nullptr,
                                                    out, 8192, 1024, 1024, 1024, 0);
}

// Round 5
// 608.306 us; speedup vs baseline: 1.1337x; 1.0534x over previous
//
#include <hip/hip_runtime.h>

typedef unsigned short u16;
typedef unsigned int u32;
typedef __attribute__((ext_vector_type(8))) short short8;
typedef __attribute__((ext_vector_type(4))) float floatx4;

__device__ __forceinline__ float bf2f(u16 x) {
    union { u32 u; float f; } c; c.u = ((u32)x) << 16; return c.f;
}
__device__ __forceinline__ u16 f2bf(float f) {
    union { float f; u32 u; } c; c.f = f;
    return (u16)((c.u + 0x7FFFu + ((c.u >> 16) & 1u)) >> 16);
}
// pack two f32 -> one u32 of 2x bf16 (RNE). Portable (no inline asm; per
// m240 the compiler schedules scalar casts better than hand-written cvt_pk).
__device__ __forceinline__ u32 pack_bf16(float lo, float hi) {
    return ((u32)f2bf(lo)) | (((u32)f2bf(hi)) << 16);
}

// async global->LDS, 16B per lane. LDS dest = wave-uniform base + lane*16.
#define GLD_LDS(g, l) __builtin_amdgcn_global_load_lds( \
    (const __attribute__((address_space(1))) u32*)(g),  \
    (__attribute__((address_space(3))) u32*)(l), 16, 0, 0)

// ---------------- f32 -> bf16 convert (optional fused relu) ----------------

__global__ void cvt_kernel(const float* __restrict__ src, u16* __restrict__ dst,
                           int n8, int do_relu) {
    int i = blockIdx.x * 256 + threadIdx.x;
    if (i >= n8) return;
    float4 a = ((const float4*)src)[2 * i];
    float4 b = ((const float4*)src)[2 * i + 1];
    float v[8] = {a.x, a.y, a.z, a.w, b.x, b.y, b.z, b.w};
    short8 o;
#pragma unroll
    for (int j = 0; j < 8; j++) {
        float x = v[j];
        if (do_relu) x = fmaxf(x, 0.f);
        o[j] = (short)f2bf(x);
    }
    ((short8*)dst)[i] = o;
}

// ---------------- stats / gates (pure f32) ----------------

// column mean over sequence: x [B,N,1024] f32 -> out [B*1024] f32 (pre-zeroed)
__global__ void mean_kernel(const float* __restrict__ x, float* __restrict__ out,
                            int N, int chunk) {
    int idx = blockIdx.x * 256 + threadIdx.x;   // (b,d) in [0, 8192)
    int b = idx >> 10, d = idx & 1023;
    int nlo = blockIdx.y * chunk;
    const float* p = x + (size_t)b * N * 1024 + (size_t)nlo * 1024 + d;
    float s = 0.f;
    for (int n = 0; n < chunk; n++) s += p[(size_t)n * 1024];
    atomicAdd(out + idx, s * (1.0f / (float)N));
}

// gate[b,n] = 1 + sigmoid( relu(mean[b,:]) . Wg[n,:] + bg[n] ), one wave/output
__global__ __launch_bounds__(256) void gate_kernel(const float* __restrict__ mean,
                                                   const float* __restrict__ Wg,
                                                   const float* __restrict__ bg,
                                                   float* __restrict__ gout) {
    int gw = blockIdx.x * 4 + (threadIdx.x >> 6);   // [0, 8192)
    int lane = threadIdx.x & 63;
    int b = gw >> 10, n = gw & 1023;
    const float* wr = Wg + (size_t)n * 1024;
    const float* mr = mean + b * 1024;
    float acc = 0.f;
    for (int k = lane; k < 1024; k += 64)
        acc += fmaxf(mr[k], 0.f) * wr[k];
#pragma unroll
    for (int m = 1; m < 64; m <<= 1) acc += __shfl_xor(acc, m, 64);
    if (lane == 0) {
        float xg = acc + bg[n];
        gout[gw] = 1.f + 1.f / (1.f + __expf(-xg));
    }
}

// residual: c_bf16[i] = a_f32[i] + b_bf16[i]
__global__ void add_kernel(const float* __restrict__ a, const u16* __restrict__ b,
                           u16* __restrict__ c, int n) {
    int i = blockIdx.x * 256 + threadIdx.x;
    if (i >= n) return;
    c[i] = f2bf(a[i] + bf2f(b[i]));
}

// ---------------- GEMM: C[M,N] = A[M,K] . W[N,K]^T + bias, optional (1+gate) ----------------
// A, W bf16 (pre-converted in ws). 128x128 tile, BK=32, 4 waves (2x2), each
// wave 4x4 MFMA 16x16x32. m97-style GLD_LDS staging. XCD-aware bijective
// block swizzle (all grids have nwg % 8 == 0). Output bf16 (Ch) or f32 (Cf).

__global__ __launch_bounds__(256) void gemm_bt_kernel(
    const u16* __restrict__ A, const u16* __restrict__ W,
    const float* __restrict__ bias, const float* __restrict__ gate,
    u16* __restrict__ Ch, float* __restrict__ Cf,
    int M, int N, int K, int seq, int gateN)
{
    __shared__ u16 As[128 * 32];   // [m][k] row-major, 8 KB
    __shared__ u16 Bs[128 * 32];   // [n][k] row-major, 8 KB

    const int tid = threadIdx.x;
    const int wave = tid >> 6, lane = tid & 63, quad = lane >> 4, l15 = lane & 15;

    // XCD swizzle: contiguous grid chunk per XCD (bijective since nwg%8==0)
    const u32 gx = gridDim.x;
    const u32 flat = blockIdx.y * gx + blockIdx.x;
    const u32 per = (gx * gridDim.y) >> 3;
    const u32 swz = (flat & 7) * per + (flat >> 3);
    const int m0 = (int)(swz / gx) * 128, n0 = (int)(swz % gx) * 128;

    const int wm = (wave >> 1) * 64, wn = (wave & 1) * 64;

    floatx4 acc[4][4] = {};

    // staging map: round r covers tile bytes [r*4096 + wave*1024 + lane*16, +16)
    const int e0 = (wave * 1024 + lane * 16) >> 1;       // elements, round 0
    const int sr0 = e0 >> 5, sc0 = e0 & 31;
    const int e1 = e0 + 2048;                            // round 1
    const int sr1 = e1 >> 5, sc1 = e1 & 31;
    const size_t aoff0 = (size_t)(m0 + sr0) * K + sc0;
    const size_t aoff1 = (size_t)(m0 + sr1) * K + sc1;
    const size_t boff0 = (size_t)(n0 + sr0) * K + sc0;
    const size_t boff1 = (size_t)(n0 + sr1) * K + sc1;

    for (int k0 = 0; k0 < K; k0 += 32) {
        GLD_LDS(A + aoff0 + k0, As + wave * 512);
        GLD_LDS(A + aoff1 + k0, As + 2048 + wave * 512);
        GLD_LDS(W + boff0 + k0, Bs + wave * 512);
        GLD_LDS(W + boff1 + k0, Bs + 2048 + wave * 512);
        __syncthreads();

        short8 af[4], bfr[4];
#pragma unroll
        for (int i = 0; i < 4; i++) {
            af[i]  = *(const short8*)(As + (wm + i * 16 + l15) * 32 + quad * 8);
            bfr[i] = *(const short8*)(Bs + (wn + i * 16 + l15) * 32 + quad * 8);
        }
#pragma unroll
        for (int mi = 0; mi < 4; mi++)
#pragma unroll
            for (int ni = 0; ni < 4; ni++)
                acc[mi][ni] = __builtin_amdgcn_mfma_f32_16x16x32_bf16(af[mi], bfr[ni], acc[mi][ni], 0, 0, 0);
        __syncthreads();
    }

    const int b = m0 / seq;
#pragma unroll
    for (int ni = 0; ni < 4; ni++) {
        const int ncol = n0 + wn + ni * 16 + l15;
        const float bsv = bias[ncol];
        float g = 1.f;
        if (gate != nullptr && ncol < gateN) g = gate[b * 1024 + (ncol & 1023)];
#pragma unroll
        for (int mi = 0; mi < 4; mi++) {
            const int row = m0 + wm + mi * 16 + quad * 4;
#pragma unroll
            for (int r = 0; r < 4; r++) {
                float val = (acc[mi][ni][r] + bsv) * g;
                size_t idx = (size_t)(row + r) * N + ncol;
                if (Cf) Cf[idx] = val; else Ch[idx] = f2bf(val);
            }
        }
    }
}

// ---------------- fused flash attention ----------------
// T: [B, N, 3072] bf16 gated trans (k | q | v thirds, 8 heads x 128 each).
// U: [B, N, 1024] bf16 update. Block = (128 q-rows, b*8+h). 4 waves x 32 rows.
// KVBLK=64, double-buffered K/V (T3) + issue-early/write-late V (T14).
// SWAPPED QK^T (T12): mfma(K,Q) makes P row-local to lane (q = l15), so
// softmax row-reduce = in-reg tree + 2 shuffles, and P packs lane-locally
// into u32 LDS words (stride-36 rows, 16B aligned, 2-way write banks).
// Defer-max (T13, THR=8) skips O-rescale on most tiles. Softmax state
// (mrow/lrow) lives at row=l15; O rows are quad*4+r, so the rare rescale
// and the epilogue broadcast alpha/l via __shfl.

__global__ __launch_bounds__(256) void attn_kernel(
    const u16* __restrict__ T, u16* __restrict__ U, int N)
{
    __shared__ __align__(16) u16 Ks[2][64 * 128];  // 2 x 16 KB, swizzled [kv][d]
    __shared__ __align__(16) u16 Vs[2][128 * 64];  // 2 x 16 KB, swizzled [d][kv]
    __shared__ __align__(16) u32 Ps32[4][16 * 36]; // 9 KB, per-wave packed P (16 rows, reused per mi)

    const int tid = threadIdx.x;
    const int wave = tid >> 6, lane = tid & 63, quad = lane >> 4, l15 = lane & 15;
    const int qb = blockIdx.x;
    const int b = blockIdx.y >> 3, h = blockIdx.y & 7;

    const size_t base = (size_t)b * N * 3072;
    const int kcol = h * 128, qcol = 1024 + h * 128, vcol = 2048 + h * 128;

    // Q fragments held in registers for the whole pass
    short8 qf[2][4];
    const int qrow0 = qb * 128 + wave * 32;
#pragma unroll
    for (int mi = 0; mi < 2; mi++)
#pragma unroll
        for (int c = 0; c < 4; c++)
            qf[mi][c] = *(const short8*)(T + base + (size_t)(qrow0 + mi * 16 + l15) * 3072
                                           + qcol + c * 32 + quad * 8);

    floatx4 o[2][8] = {};
    float mrow[2], lrow[2];
#pragma unroll
    for (int mi = 0; mi < 2; mi++) { mrow[mi] = -1e30f; lrow[mi] = 0.f; }

    const float scale = 0.08838834764831845f;  // 1/sqrt(128)

    // K staging map: round r covers Ks bytes [r*4096 + wave*1024 + lane*16, +16).
    // LDS byte ob holds K[kv = ob>>8][d = (((ob>>4)&15) ^ (kv&15))*8 .. +8)
    int kst_kv[4], kst_d[4];
#pragma unroll
    for (int r = 0; r < 4; r++) {
        int ob = r * 4096 + wave * 1024 + lane * 16;
        int kv = ob >> 8;
        kst_kv[r] = kv;
        kst_d[r] = ((((ob >> 4) & 15) ^ (kv & 15)) << 3);
    }
    // V staging map: 32 distinct banks per store across a wave
    const int vkv = (tid & 31) * 2;     // kv pair base
    const int vd8 = tid >> 5;           // [0,8)

    // ---- prologue: stage tile 0 ----
    short8 vr0[2], vr1[2];
#pragma unroll
    for (int r = 0; r < 4; r++)
        GLD_LDS(T + base + (size_t)kst_kv[r] * 3072 + kcol + kst_d[r],
                Ks[0] + r * 2048 + wave * 512);
#pragma unroll
    for (int pp = 0; pp < 2; pp++) {
        const u16* vp0 = T + base + (size_t)vkv * 3072 + vcol + (vd8 + 8 * pp) * 8;
        vr0[pp] = *(const short8*)vp0;
        vr1[pp] = *(const short8*)(vp0 + 3072);
    }
#pragma unroll
    for (int pp = 0; pp < 2; pp++) {
        const int dbase = (vd8 + 8 * pp) * 8;
#pragma unroll
        for (int j = 0; j < 8; j++) {
            u32 wv = ((u32)(u16)vr0[pp][j]) | (((u32)(u16)vr1[pp][j]) << 16);
            *(u32*)((char*)Vs[0] + (size_t)(dbase + j) * 128
                    + ((((vkv >> 3) ^ j)) << 4) + ((vkv * 2) & 15)) = wv;
        }
    }
    __syncthreads();

    int cur = 0;
    for (int kt = 0; kt < N; kt += 64) {
        const int nxt = cur ^ 1;
        const bool more = (kt + 64) < N;

        // ---- issue next tile's staging EARLY (hides under compute) ----
        if (more) {
#pragma unroll
            for (int r = 0; r < 4; r++)
                GLD_LDS(T + base + (size_t)(kt + 64 + kst_kv[r]) * 3072 + kcol + kst_d[r],
                        Ks[nxt] + r * 2048 + wave * 512);
#pragma unroll
            for (int pp = 0; pp < 2; pp++) {
                const u16* vp0 = T + base + (size_t)(kt + 64 + vkv) * 3072 + vcol + (vd8 + 8 * pp) * 8;
                vr0[pp] = *(const short8*)vp0;
                vr1[pp] = *(const short8*)(vp0 + 3072);
            }
        }

        // ---- QK^T (swapped: mfma(K,Q) -> S^T). p[mi][ni][r] = P[q=l15+16mi][kv=ni*16+quad*4+r]
        float p[2][4][4];
        __builtin_amdgcn_s_setprio(1);
#pragma unroll
        for (int ni = 0; ni < 4; ni++) {
            short8 kf[4];
#pragma unroll
            for (int c = 0; c < 4; c++)
                kf[c] = *(const short8*)(Ks[cur] + (ni * 16 + l15) * 128
                                            + (((c * 4 + quad) ^ l15) << 3));
#pragma unroll
            for (int mi = 0; mi < 2; mi++) {
                floatx4 s = {0.f, 0.f, 0.f, 0.f};
#pragma unroll
                for (int c = 0; c < 4; c++)
                    s = __builtin_amdgcn_mfma_f32_16x16x32_bf16(kf[c], qf[mi][c], s, 0, 0, 0);
#pragma unroll
                for (int r = 0; r < 4; r++) p[mi][ni][r] = s[r] * scale;
            }
        }
        __builtin_amdgcn_s_setprio(0);

        // ---- online softmax, lane-local rows (q = l15), defer-max THR=8 ----
#pragma unroll
        for (int mi = 0; mi < 2; mi++) {
            float tm = p[mi][0][0];
#pragma unroll
            for (int ni = 0; ni < 4; ni++)
#pragma unroll
                for (int r = 0; r < 4; r++) tm = fmaxf(tm, p[mi][ni][r]);
            tm = fmaxf(tm, __shfl_xor(tm, 16, 64));
            tm = fmaxf(tm, __shfl_xor(tm, 32, 64));
            const bool need = __any(tm > mrow[mi] + 8.f);   // wave-uniform
            if (need) {
                float mnew = fmaxf(mrow[mi], tm);
                float alpha = __expf(mrow[mi] - mnew);
                mrow[mi] = mnew;
                float ps = 0.f;
#pragma unroll
                for (int ni = 0; ni < 4; ni++)
#pragma unroll
                    for (int r = 0; r < 4; r++) {
                        float pe = __expf(p[mi][ni][r] - mnew);
                        p[mi][ni][r] = pe;
                        ps += pe;
                    }
                ps += __shfl_xor(ps, 16, 64);
                ps += __shfl_xor(ps, 32, 64);
                lrow[mi] = lrow[mi] * alpha + ps;
                // broadcast alpha (state row l15) to O rows (quad*4+r)
#pragma unroll
                for (int r = 0; r < 4; r++) {
                    float ab = __shfl(alpha, quad * 4 + r, 64);
#pragma unroll
                    for (int nt = 0; nt < 8; nt++) o[mi][nt][r] *= ab;
                }
            } else {
                const float mref = mrow[mi];
                float ps = 0.f;
#pragma unroll
                for (int ni = 0; ni < 4; ni++)
#pragma unroll
                    for (int r = 0; r < 4; r++) {
                        float pe = __expf(p[mi][ni][r] - mref);
                        p[mi][ni][r] = pe;
                        ps += pe;
                    }
                ps += __shfl_xor(ps, 16, 64);
                ps += __shfl_xor(ps, 32, 64);
                lrow[mi] += ps;
            }
        }

        // ---- P pack -> LDS (16-row buffer reused per mi) -> PV A-frags ----
        short8 pf[2][2];
#pragma unroll
        for (int mi = 0; mi < 2; mi++) {
            // write 8 packed words: kv pair (ni*16+quad*4+2s, +1) -> word ni*8+quad*2+s
#pragma unroll
            for (int ni = 0; ni < 4; ni++)
#pragma unroll
                for (int s = 0; s < 2; s++)
                    Ps32[wave][l15 * 36 + ni * 8 + quad * 2 + s]
                        = pack_bf16(p[mi][ni][2 * s], p[mi][ni][2 * s + 1]);
            // read A-frag: P[q=l15][kv = kc*32 + quad*8 + j], words kc*16+quad*4 .. +3
#pragma unroll
            for (int kc = 0; kc < 2; kc++)
                pf[mi][kc] = *(const short8*)(&Ps32[wave][l15 * 36 + kc * 16 + quad * 4]);
        }

        // ---- PV: 32 MFMA, swizzled conflict-free V reads ----
        __builtin_amdgcn_s_setprio(1);
#pragma unroll
        for (int nt = 0; nt < 8; nt++) {
#pragma unroll
            for (int kc = 0; kc < 2; kc++) {
                short8 vf = *(const short8*)(Vs[cur] + (nt * 16 + l15) * 64
                                + (((kc * 4 + quad) ^ (l15 & 7)) << 3));
#pragma unroll
                for (int mi = 0; mi < 2; mi++)
                    o[mi][nt] = __builtin_amdgcn_mfma_f32_16x16x32_bf16(pf[mi][kc], vf, o[mi][nt], 0, 0, 0);
            }
        }
        __builtin_amdgcn_s_setprio(0);

        // ---- late V write into next buffer (loads drained under compute) ----
        if (more) {
#pragma unroll
            for (int pp = 0; pp < 2; pp++) {
                const int dbase = (vd8 + 8 * pp) * 8;
#pragma unroll
                for (int j = 0; j < 8; j++) {
                    u32 wv = ((u32)(u16)vr0[pp][j]) | (((u32)(u16)vr1[pp][j]) << 16);
                    *(u32*)((char*)Vs[nxt] + (size_t)(dbase + j) * 128
                            + ((((vkv >> 3) ^ j)) << 4) + ((vkv * 2) & 15)) = wv;
                }
            }
        }
        __syncthreads();
        cur = nxt;
    }

    // ---- epilogue: broadcast l (state row l15 -> O row quad*4+r), store U ----
    const size_t ub = (size_t)b * N * 1024;
#pragma unroll
    for (int mi = 0; mi < 2; mi++)
#pragma unroll
        for (int r = 0; r < 4; r++) {
            float lb = __shfl(lrow[mi], quad * 4 + r, 64);
            float inv = 1.f / lb;
            const size_t row = qb * 128 + wave * 32 + mi * 16 + quad * 4 + r;
#pragma unroll
            for (int nt = 0; nt < 8; nt++)
                U[ub + row * 1024 + h * 128 + nt * 16 + l15] = f2bf(o[mi][nt][r] * inv);
        }
}

// ---------------- launch ----------------
// Inputs f32, outputs f32 (both per reference dtypes). ws peak = 80.1 MB:
// stats 128 KB | weights 8 MB @1MB | activations 16 MB @16MB | trans 48 MB @32MB.
// q phase then v phase reuse the same regions sequentially.

extern "C" void kernel_launch(void* const* d_in, const int* in_sizes, int n_in,
                              void* d_out, int out_size, void* d_ws, size_t ws_size,
                              hipStream_t stream) {
    (void)in_sizes; (void)n_in; (void)out_size; (void)ws_size;
    const float* v   = (const float*)d_in[0];
    const float* q   = (const float*)d_in[1];
    const float* Wg_v4q = (const float*)d_in[2];
    const float* bg_v4q = (const float*)d_in[3];
    const float* Wg_q4v = (const float*)d_in[4];
    const float* bg_q4v = (const float*)d_in[5];
    const float* Wv  = (const float*)d_in[6];
    const float* bv  = (const float*)d_in[7];
    const float* Wq  = (const float*)d_in[8];
    const float* bq  = (const float*)d_in[9];
    const float* Wvo = (const float*)d_in[10];
    const float* bvo = (const float*)d_in[11];
    const float* Wqo = (const float*)d_in[12];
    const float* bqo = (const float*)d_in[13];
    float* out = (float*)d_out;                     // [v: 8388608][q: 4194304] f32

    char* w = (char*)d_ws;
    float* vmean = (float*)(w + 0);                 // 32 KB
    float* qmean = (float*)(w + 32768);
    float* gv4q  = (float*)(w + 65536);
    float* gq4v  = (float*)(w + 98304);
    u16* cWt  = (u16*)(w + (1 << 20));              // 6 MB (trans weight bf16)
    u16* cWo  = (u16*)(w + (1 << 20) + 6291456);    // 2 MB (proj weight bf16)
    u16* aReg = (u16*)(w + (16 << 20));             // 16 MB (relu acts / updates)
    u16* tReg = (u16*)(w + (32 << 20));             // 48 MB (trans / residual sum)

    // stats + gates
    hipMemsetAsync(vmean, 0, 65536, stream);        // covers vmean + qmean
    mean_kernel<<<dim3(32, 8), 256, 0, stream>>>(v, vmean, 1024, 128);
    mean_kernel<<<dim3(32, 8), 256, 0, stream>>>(q, qmean, 512, 64);
    gate_kernel<<<2048, 256, 0, stream>>>(vmean, Wg_v4q, bg_v4q, gv4q);  // for q pipeline
    gate_kernel<<<2048, 256, 0, stream>>>(qmean, Wg_q4v, bg_q4v, gq4v);  // for v pipeline

    // ---- q phase ----
    u16* crq  = aReg;                               // bf16 relu(q), 8 MB
    u16* qt   = tReg;                               // [8,512,3072] bf16, 24 MB
    u16* qupd = aReg;                               // reuses crq after trans GEMM
    u16* qsum = tReg;                               // reuses qt after attention
    cvt_kernel<<<2048, 256, 0, stream>>>(q, crq, 524288, 1);
    cvt_kernel<<<1536, 256, 0, stream>>>(Wq, cWt, 393216, 0);
    cvt_kernel<<<512, 256, 0, stream>>>(Wqo, cWo, 131072, 0);
    gemm_bt_kernel<<<dim3(24, 32), 256, 0, stream>>>(crq, cWt, bq, gv4q, qt, nullptr,
                                                     4096, 3072, 1024, 512, 2048);
    attn_kernel<<<dim3(4, 64), 256, 0, stream>>>(qt, qupd, 512);
    add_kernel<<<16384, 256, 0, stream>>>(q, qupd, qsum, 4194304);
    gemm_bt_kernel<<<dim3(8, 32), 256, 0, stream>>>(qsum, cWo, bqo, nullptr, nullptr,
                                                    out + 8388608, 4096, 1024, 1024, 512, 0);

    // ---- v phase ----
    u16* crv  = aReg;                               // bf16 relu(v), 16 MB
    u16* vt   = tReg;                               // [8,1024,3072] bf16, 48 MB
    u16* vupd = aReg;
    u16* vsum = tReg;
    cvt_kernel<<<4096, 256, 0, stream>>>(v, crv, 1048576, 1);
    cvt_kernel<<<1536, 256, 0, stream>>>(Wv, cWt, 393216, 0);
    cvt_kernel<<<512, 256, 0, stream>>>(Wvo, cWo, 131072, 0);
    gemm_bt_kernel<<<dim3(24, 64), 256, 0, stream>>>(crv, cWt, bv, gq4v, vt, nullptr,
                                                     8192, 3072, 1024, 1024, 2048);
    attn_kernel<<<dim3(8, 64), 256, 0, stream>>>(vt, vupd, 1024);
    add_kernel<<<32768, 256, 0, stream>>>(v, vupd, vsum, 8388608);
    gemm_bt_kernel<<<dim3(8, 64), 256, 0, stream>>>(vsum, cWo, bvo, nullptr, nullptr,
                                                    out, 8192, 1024, 1024, 1024, 0);
}

// Round 6
// 574.737 us; speedup vs baseline: 1.1999x; 1.0584x over previous
//
#include <hip/hip_runtime.h>

typedef unsigned short u16;
typedef unsigned int u32;
typedef __attribute__((ext_vector_type(8))) short short8;
typedef __attribute__((ext_vector_type(4))) float floatx4;

__device__ __forceinline__ float bf2f(u16 x) {
    union { u32 u; float f; } c; c.u = ((u32)x) << 16; return c.f;
}
__device__ __forceinline__ u16 f2bf(float f) {
    union { float f; u32 u; } c; c.f = f;
    return (u16)((c.u + 0x7FFFu + ((c.u >> 16) & 1u)) >> 16);
}
// pack two f32 -> one u32 of 2x bf16 (RNE). Portable (no inline asm; per
// m240 the compiler schedules scalar casts better than hand-written cvt_pk).
__device__ __forceinline__ u32 pack_bf16(float lo, float hi) {
    return ((u32)f2bf(lo)) | (((u32)f2bf(hi)) << 16);
}

// async global->LDS, 16B per lane. LDS dest = wave-uniform base + lane*16.
#define GLD_LDS(g, l) __builtin_amdgcn_global_load_lds( \
    (const __attribute__((address_space(1))) u32*)(g),  \
    (__attribute__((address_space(3))) u32*)(l), 16, 0, 0)

// ---------------- f32 -> bf16 convert (optional fused relu) ----------------

__global__ void cvt_kernel(const float* __restrict__ src, u16* __restrict__ dst,
                           int n8, int do_relu) {
    int i = blockIdx.x * 256 + threadIdx.x;
    if (i >= n8) return;
    float4 a = ((const float4*)src)[2 * i];
    float4 b = ((const float4*)src)[2 * i + 1];
    float v[8] = {a.x, a.y, a.z, a.w, b.x, b.y, b.z, b.w};
    short8 o;
#pragma unroll
    for (int j = 0; j < 8; j++) {
        float x = v[j];
        if (do_relu) x = fmaxf(x, 0.f);
        o[j] = (short)f2bf(x);
    }
    ((short8*)dst)[i] = o;
}

// ---------------- stats / gates (pure f32) ----------------

// column mean over sequence: x [B,N,1024] f32 -> out [B*1024] f32 (pre-zeroed)
__global__ void mean_kernel(const float* __restrict__ x, float* __restrict__ out,
                            int N, int chunk) {
    int idx = blockIdx.x * 256 + threadIdx.x;   // (b,d) in [0, 8192)
    int b = idx >> 10, d = idx & 1023;
    int nlo = blockIdx.y * chunk;
    const float* p = x + (size_t)b * N * 1024 + (size_t)nlo * 1024 + d;
    float s = 0.f;
    for (int n = 0; n < chunk; n++) s += p[(size_t)n * 1024];
    atomicAdd(out + idx, s * (1.0f / (float)N));
}

// gate[b,n] = 1 + sigmoid( relu(mean[b,:]) . Wg[n,:] + bg[n] ), one wave/output
__global__ __launch_bounds__(256) void gate_kernel(const float* __restrict__ mean,
                                                   const float* __restrict__ Wg,
                                                   const float* __restrict__ bg,
                                                   float* __restrict__ gout) {
    int gw = blockIdx.x * 4 + (threadIdx.x >> 6);   // [0, 8192)
    int lane = threadIdx.x & 63;
    int b = gw >> 10, n = gw & 1023;
    const float* wr = Wg + (size_t)n * 1024;
    const float* mr = mean + b * 1024;
    float acc = 0.f;
    for (int k = lane; k < 1024; k += 64)
        acc += fmaxf(mr[k], 0.f) * wr[k];
#pragma unroll
    for (int m = 1; m < 64; m <<= 1) acc += __shfl_xor(acc, m, 64);
    if (lane == 0) {
        float xg = acc + bg[n];
        gout[gw] = 1.f + 1.f / (1.f + __expf(-xg));
    }
}

// ---------------- GEMM: C[M,N] = A[M,K] . W[N,K]^T + bias, optional (1+gate) ----------------
// A, W bf16 (pre-converted in ws). 128x128 tile, BK=32, 4 waves (2x2), each
// wave 4x4 MFMA 16x16x32. DOUBLE-BUFFERED GLD_LDS staging (T3 2-phase):
// next K-tile's async DMA issues BEFORE current tile's compute, so the
// barrier's vmcnt(0) drain lands after compute covered the fetch latency.
// XCD-aware bijective block swizzle (all grids nwg % 8 == 0).
// Output bf16 (Ch) or f32 (Cf), exactly one non-null.

__global__ __launch_bounds__(256) void gemm_bt_kernel(
    const u16* __restrict__ A, const u16* __restrict__ W,
    const float* __restrict__ bias, const float* __restrict__ gate,
    u16* __restrict__ Ch, float* __restrict__ Cf,
    int M, int N, int K, int seq, int gateN)
{
    __shared__ u16 As[2][128 * 32];   // [m][k] row-major, 2 x 8 KB
    __shared__ u16 Bs[2][128 * 32];   // [n][k] row-major, 2 x 8 KB

    const int tid = threadIdx.x;
    const int wave = tid >> 6, lane = tid & 63, quad = lane >> 4, l15 = lane & 15;

    // XCD swizzle: contiguous grid chunk per XCD (bijective since nwg%8==0)
    const u32 gx = gridDim.x;
    const u32 flat = blockIdx.y * gx + blockIdx.x;
    const u32 per = (gx * gridDim.y) >> 3;
    const u32 swz = (flat & 7) * per + (flat >> 3);
    const int m0 = (int)(swz / gx) * 128, n0 = (int)(swz % gx) * 128;

    const int wm = (wave >> 1) * 64, wn = (wave & 1) * 64;

    floatx4 acc[4][4] = {};

    // staging map: round r covers tile bytes [r*4096 + wave*1024 + lane*16, +16)
    const int e0 = (wave * 1024 + lane * 16) >> 1;       // elements, round 0
    const int sr0 = e0 >> 5, sc0 = e0 & 31;
    const int e1 = e0 + 2048;                            // round 1
    const int sr1 = e1 >> 5, sc1 = e1 & 31;
    const size_t aoff0 = (size_t)(m0 + sr0) * K + sc0;
    const size_t aoff1 = (size_t)(m0 + sr1) * K + sc1;
    const size_t boff0 = (size_t)(n0 + sr0) * K + sc0;
    const size_t boff1 = (size_t)(n0 + sr1) * K + sc1;

    // prologue: stage K-tile 0 into buffer 0
    GLD_LDS(A + aoff0, As[0] + wave * 512);
    GLD_LDS(A + aoff1, As[0] + 2048 + wave * 512);
    GLD_LDS(W + boff0, Bs[0] + wave * 512);
    GLD_LDS(W + boff1, Bs[0] + 2048 + wave * 512);
    __syncthreads();

    int cur = 0;
    for (int k0 = 0; k0 < K; k0 += 32) {
        const int nxt = cur ^ 1;
        // issue next tile's DMA early (hides under this tile's compute)
        if (k0 + 32 < K) {
            GLD_LDS(A + aoff0 + k0 + 32, As[nxt] + wave * 512);
            GLD_LDS(A + aoff1 + k0 + 32, As[nxt] + 2048 + wave * 512);
            GLD_LDS(W + boff0 + k0 + 32, Bs[nxt] + wave * 512);
            GLD_LDS(W + boff1 + k0 + 32, Bs[nxt] + 2048 + wave * 512);
        }

        short8 af[4], bfr[4];
#pragma unroll
        for (int i = 0; i < 4; i++) {
            af[i]  = *(const short8*)(As[cur] + (wm + i * 16 + l15) * 32 + quad * 8);
            bfr[i] = *(const short8*)(Bs[cur] + (wn + i * 16 + l15) * 32 + quad * 8);
        }
#pragma unroll
        for (int mi = 0; mi < 4; mi++)
#pragma unroll
            for (int ni = 0; ni < 4; ni++)
                acc[mi][ni] = __builtin_amdgcn_mfma_f32_16x16x32_bf16(af[mi], bfr[ni], acc[mi][ni], 0, 0, 0);
        __syncthreads();
        cur = nxt;
    }

    const int b = m0 / seq;
#pragma unroll
    for (int ni = 0; ni < 4; ni++) {
        const int ncol = n0 + wn + ni * 16 + l15;
        const float bsv = bias[ncol];
        float g = 1.f;
        if (gate != nullptr && ncol < gateN) g = gate[b * 1024 + (ncol & 1023)];
#pragma unroll
        for (int mi = 0; mi < 4; mi++) {
            const int row = m0 + wm + mi * 16 + quad * 4;
#pragma unroll
            for (int r = 0; r < 4; r++) {
                float val = (acc[mi][ni][r] + bsv) * g;
                size_t idx = (size_t)(row + r) * N + ncol;
                if (Cf) Cf[idx] = val; else Ch[idx] = f2bf(val);
            }
        }
    }
}

// ---------------- fused flash attention (+ fused residual epilogue) ----------------
// T: [B, N, 3072] bf16 gated trans (k | q | v thirds, 8 heads x 128 each).
// X: [B, N, 1024] f32 original input (v or q) for the residual.
// U: [B, N, 1024] bf16 out = bf16(X + attn). Block = (128 q-rows, b*8+h).
// 4 waves x 32 rows. KVBLK=64, double-buffered K/V (T3) + issue-early/
// write-late V (T14). SWAPPED QK^T (T12): mfma(K,Q) makes P row-local to
// lane (q = l15): softmax row-reduce = in-reg tree + 2 shuffles; P packs
// lane-locally into u32 LDS words (stride-36 rows, 16B aligned). Defer-max
// (T13, THR=8) skips O-rescale on most tiles. Softmax state lives at
// row=l15; O rows are quad*4+r; alpha/l broadcast via __shfl.

__global__ __launch_bounds__(256) void attn_kernel(
    const u16* __restrict__ T, const float* __restrict__ X,
    u16* __restrict__ U, int N)
{
    __shared__ __align__(16) u16 Ks[2][64 * 128];  // 2 x 16 KB, swizzled [kv][d]
    __shared__ __align__(16) u16 Vs[2][128 * 64];  // 2 x 16 KB, swizzled [d][kv]
    __shared__ __align__(16) u32 Ps32[4][16 * 36]; // 9 KB, per-wave packed P

    const int tid = threadIdx.x;
    const int wave = tid >> 6, lane = tid & 63, quad = lane >> 4, l15 = lane & 15;
    const int qb = blockIdx.x;
    const int b = blockIdx.y >> 3, h = blockIdx.y & 7;

    const size_t base = (size_t)b * N * 3072;
    const int kcol = h * 128, qcol = 1024 + h * 128, vcol = 2048 + h * 128;

    // Q fragments held in registers for the whole pass
    short8 qf[2][4];
    const int qrow0 = qb * 128 + wave * 32;
#pragma unroll
    for (int mi = 0; mi < 2; mi++)
#pragma unroll
        for (int c = 0; c < 4; c++)
            qf[mi][c] = *(const short8*)(T + base + (size_t)(qrow0 + mi * 16 + l15) * 3072
                                           + qcol + c * 32 + quad * 8);

    floatx4 o[2][8] = {};
    float mrow[2], lrow[2];
#pragma unroll
    for (int mi = 0; mi < 2; mi++) { mrow[mi] = -1e30f; lrow[mi] = 0.f; }

    const float scale = 0.08838834764831845f;  // 1/sqrt(128)

    // K staging map: round r covers Ks bytes [r*4096 + wave*1024 + lane*16, +16).
    // LDS byte ob holds K[kv = ob>>8][d = (((ob>>4)&15) ^ (kv&15))*8 .. +8)
    int kst_kv[4], kst_d[4];
#pragma unroll
    for (int r = 0; r < 4; r++) {
        int ob = r * 4096 + wave * 1024 + lane * 16;
        int kv = ob >> 8;
        kst_kv[r] = kv;
        kst_d[r] = ((((ob >> 4) & 15) ^ (kv & 15)) << 3);
    }
    // V staging map: 32 distinct banks per store across a wave
    const int vkv = (tid & 31) * 2;     // kv pair base
    const int vd8 = tid >> 5;           // [0,8)

    // ---- prologue: stage tile 0 ----
    short8 vr0[2], vr1[2];
#pragma unroll
    for (int r = 0; r < 4; r++)
        GLD_LDS(T + base + (size_t)kst_kv[r] * 3072 + kcol + kst_d[r],
                Ks[0] + r * 2048 + wave * 512);
#pragma unroll
    for (int pp = 0; pp < 2; pp++) {
        const u16* vp0 = T + base + (size_t)vkv * 3072 + vcol + (vd8 + 8 * pp) * 8;
        vr0[pp] = *(const short8*)vp0;
        vr1[pp] = *(const short8*)(vp0 + 3072);
    }
#pragma unroll
    for (int pp = 0; pp < 2; pp++) {
        const int dbase = (vd8 + 8 * pp) * 8;
#pragma unroll
        for (int j = 0; j < 8; j++) {
            u32 wv = ((u32)(u16)vr0[pp][j]) | (((u32)(u16)vr1[pp][j]) << 16);
            *(u32*)((char*)Vs[0] + (size_t)(dbase + j) * 128
                    + ((((vkv >> 3) ^ j)) << 4) + ((vkv * 2) & 15)) = wv;
        }
    }
    __syncthreads();

    int cur = 0;
    for (int kt = 0; kt < N; kt += 64) {
        const int nxt = cur ^ 1;
        const bool more = (kt + 64) < N;

        // ---- issue next tile's staging EARLY (hides under compute) ----
        if (more) {
#pragma unroll
            for (int r = 0; r < 4; r++)
                GLD_LDS(T + base + (size_t)(kt + 64 + kst_kv[r]) * 3072 + kcol + kst_d[r],
                        Ks[nxt] + r * 2048 + wave * 512);
#pragma unroll
            for (int pp = 0; pp < 2; pp++) {
                const u16* vp0 = T + base + (size_t)(kt + 64 + vkv) * 3072 + vcol + (vd8 + 8 * pp) * 8;
                vr0[pp] = *(const short8*)vp0;
                vr1[pp] = *(const short8*)(vp0 + 3072);
            }
        }

        // ---- QK^T (swapped: mfma(K,Q) -> S^T). p[mi][ni][r] = P[q=l15+16mi][kv=ni*16+quad*4+r]
        float p[2][4][4];
        __builtin_amdgcn_s_setprio(1);
#pragma unroll
        for (int ni = 0; ni < 4; ni++) {
            short8 kf[4];
#pragma unroll
            for (int c = 0; c < 4; c++)
                kf[c] = *(const short8*)(Ks[cur] + (ni * 16 + l15) * 128
                                            + (((c * 4 + quad) ^ l15) << 3));
#pragma unroll
            for (int mi = 0; mi < 2; mi++) {
                floatx4 s = {0.f, 0.f, 0.f, 0.f};
#pragma unroll
                for (int c = 0; c < 4; c++)
                    s = __builtin_amdgcn_mfma_f32_16x16x32_bf16(kf[c], qf[mi][c], s, 0, 0, 0);
#pragma unroll
                for (int r = 0; r < 4; r++) p[mi][ni][r] = s[r] * scale;
            }
        }
        __builtin_amdgcn_s_setprio(0);

        // ---- online softmax, lane-local rows (q = l15), defer-max THR=8 ----
#pragma unroll
        for (int mi = 0; mi < 2; mi++) {
            float tm = p[mi][0][0];
#pragma unroll
            for (int ni = 0; ni < 4; ni++)
#pragma unroll
                for (int r = 0; r < 4; r++) tm = fmaxf(tm, p[mi][ni][r]);
            tm = fmaxf(tm, __shfl_xor(tm, 16, 64));
            tm = fmaxf(tm, __shfl_xor(tm, 32, 64));
            const bool need = __any(tm > mrow[mi] + 8.f);   // wave-uniform
            if (need) {
                float mnew = fmaxf(mrow[mi], tm);
                float alpha = __expf(mrow[mi] - mnew);
                mrow[mi] = mnew;
                float ps = 0.f;
#pragma unroll
                for (int ni = 0; ni < 4; ni++)
#pragma unroll
                    for (int r = 0; r < 4; r++) {
                        float pe = __expf(p[mi][ni][r] - mnew);
                        p[mi][ni][r] = pe;
                        ps += pe;
                    }
                ps += __shfl_xor(ps, 16, 64);
                ps += __shfl_xor(ps, 32, 64);
                lrow[mi] = lrow[mi] * alpha + ps;
                // broadcast alpha (state row l15) to O rows (quad*4+r)
#pragma unroll
                for (int r = 0; r < 4; r++) {
                    float ab = __shfl(alpha, quad * 4 + r, 64);
#pragma unroll
                    for (int nt = 0; nt < 8; nt++) o[mi][nt][r] *= ab;
                }
            } else {
                const float mref = mrow[mi];
                float ps = 0.f;
#pragma unroll
                for (int ni = 0; ni < 4; ni++)
#pragma unroll
                    for (int r = 0; r < 4; r++) {
                        float pe = __expf(p[mi][ni][r] - mref);
                        p[mi][ni][r] = pe;
                        ps += pe;
                    }
                ps += __shfl_xor(ps, 16, 64);
                ps += __shfl_xor(ps, 32, 64);
                lrow[mi] += ps;
            }
        }

        // ---- P pack -> LDS (16-row buffer reused per mi) -> PV A-frags ----
        short8 pf[2][2];
#pragma unroll
        for (int mi = 0; mi < 2; mi++) {
            // write 8 packed words: kv pair (ni*16+quad*4+2s, +1) -> word ni*8+quad*2+s
#pragma unroll
            for (int ni = 0; ni < 4; ni++)
#pragma unroll
                for (int s = 0; s < 2; s++)
                    Ps32[wave][l15 * 36 + ni * 8 + quad * 2 + s]
                        = pack_bf16(p[mi][ni][2 * s], p[mi][ni][2 * s + 1]);
            // read A-frag: P[q=l15][kv = kc*32 + quad*8 + j], words kc*16+quad*4 .. +3
#pragma unroll
            for (int kc = 0; kc < 2; kc++)
                pf[mi][kc] = *(const short8*)(&Ps32[wave][l15 * 36 + kc * 16 + quad * 4]);
        }

        // ---- PV: 32 MFMA, swizzled conflict-free V reads ----
        __builtin_amdgcn_s_setprio(1);
#pragma unroll
        for (int nt = 0; nt < 8; nt++) {
#pragma unroll
            for (int kc = 0; kc < 2; kc++) {
                short8 vf = *(const short8*)(Vs[cur] + (nt * 16 + l15) * 64
                                + (((kc * 4 + quad) ^ (l15 & 7)) << 3));
#pragma unroll
                for (int mi = 0; mi < 2; mi++)
                    o[mi][nt] = __builtin_amdgcn_mfma_f32_16x16x32_bf16(pf[mi][kc], vf, o[mi][nt], 0, 0, 0);
            }
        }
        __builtin_amdgcn_s_setprio(0);

        // ---- late V write into next buffer (loads drained under compute) ----
        if (more) {
#pragma unroll
            for (int pp = 0; pp < 2; pp++) {
                const int dbase = (vd8 + 8 * pp) * 8;
#pragma unroll
                for (int j = 0; j < 8; j++) {
                    u32 wv = ((u32)(u16)vr0[pp][j]) | (((u32)(u16)vr1[pp][j]) << 16);
                    *(u32*)((char*)Vs[nxt] + (size_t)(dbase + j) * 128
                            + ((((vkv >> 3) ^ j)) << 4) + ((vkv * 2) & 15)) = wv;
                }
            }
        }
        __syncthreads();
        cur = nxt;
    }

    // ---- epilogue: broadcast l, fuse residual: U = bf16(X + O/l) ----
    const size_t ub = (size_t)b * N * 1024;
#pragma unroll
    for (int mi = 0; mi < 2; mi++)
#pragma unroll
        for (int r = 0; r < 4; r++) {
            float lb = __shfl(lrow[mi], quad * 4 + r, 64);
            float inv = 1.f / lb;
            const size_t row = qb * 128 + wave * 32 + mi * 16 + quad * 4 + r;
#pragma unroll
            for (int nt = 0; nt < 8; nt++) {
                const size_t idx = ub + row * 1024 + h * 128 + nt * 16 + l15;
                U[idx] = f2bf(X[idx] + o[mi][nt][r] * inv);
            }
        }
}

// ---------------- launch ----------------
// Inputs f32, outputs f32 (both per reference dtypes). ws peak = 80.1 MB:
// stats 128 KB | weights 8 MB @1MB | activations 16 MB @16MB | trans 48 MB @32MB.
// q phase then v phase reuse the same regions sequentially. Residual add is
// fused into attn's epilogue: attn writes bf16(X + attn) into aReg, which
// the output-proj GEMM consumes directly (aReg's prior content, the relu'd
// input, is dead after the trans GEMM; attn reads only tReg + the f32 input).

extern "C" void kernel_launch(void* const* d_in, const int* in_sizes, int n_in,
                              void* d_out, int out_size, void* d_ws, size_t ws_size,
                              hipStream_t stream) {
    (void)in_sizes; (void)n_in; (void)out_size; (void)ws_size;
    const float* v   = (const float*)d_in[0];
    const float* q   = (const float*)d_in[1];
    const float* Wg_v4q = (const float*)d_in[2];
    const float* bg_v4q = (const float*)d_in[3];
    const float* Wg_q4v = (const float*)d_in[4];
    const float* bg_q4v = (const float*)d_in[5];
    const float* Wv  = (const float*)d_in[6];
    const float* bv  = (const float*)d_in[7];
    const float* Wq  = (const float*)d_in[8];
    const float* bq  = (const float*)d_in[9];
    const float* Wvo = (const float*)d_in[10];
    const float* bvo = (const float*)d_in[11];
    const float* Wqo = (const float*)d_in[12];
    const float* bqo = (const float*)d_in[13];
    float* out = (float*)d_out;                     // [v: 8388608][q: 4194304] f32

    char* w = (char*)d_ws;
    float* vmean = (float*)(w + 0);                 // 32 KB
    float* qmean = (float*)(w + 32768);
    float* gv4q  = (float*)(w + 65536);
    float* gq4v  = (float*)(w + 98304);
    u16* cWt  = (u16*)(w + (1 << 20));              // 6 MB (trans weight bf16)
    u16* cWo  = (u16*)(w + (1 << 20) + 6291456);    // 2 MB (proj weight bf16)
    u16* aReg = (u16*)(w + (16 << 20));             // 16 MB (relu acts / residual sum)
    u16* tReg = (u16*)(w + (32 << 20));             // 48 MB (trans)

    // stats + gates
    hipMemsetAsync(vmean, 0, 65536, stream);        // covers vmean + qmean
    mean_kernel<<<dim3(32, 8), 256, 0, stream>>>(v, vmean, 1024, 128);
    mean_kernel<<<dim3(32, 8), 256, 0, stream>>>(q, qmean, 512, 64);
    gate_kernel<<<2048, 256, 0, stream>>>(vmean, Wg_v4q, bg_v4q, gv4q);  // for q pipeline
    gate_kernel<<<2048, 256, 0, stream>>>(qmean, Wg_q4v, bg_q4v, gq4v);  // for v pipeline

    // ---- q phase ----
    u16* crq  = aReg;                               // bf16 relu(q), 8 MB
    u16* qt   = tReg;                               // [8,512,3072] bf16, 24 MB
    u16* qres = aReg;                               // bf16(q + attn), overwrites crq
    cvt_kernel<<<2048, 256, 0, stream>>>(q, crq, 524288, 1);
    cvt_kernel<<<1536, 256, 0, stream>>>(Wq, cWt, 393216, 0);
    cvt_kernel<<<512, 256, 0, stream>>>(Wqo, cWo, 131072, 0);
    gemm_bt_kernel<<<dim3(24, 32), 256, 0, stream>>>(crq, cWt, bq, gv4q, qt, nullptr,
                                                     4096, 3072, 1024, 512, 2048);
    attn_kernel<<<dim3(4, 64), 256, 0, stream>>>(qt, q, qres, 512);
    gemm_bt_kernel<<<dim3(8, 32), 256, 0, stream>>>(qres, cWo, bqo, nullptr, nullptr,
                                                    out + 8388608, 4096, 1024, 1024, 512, 0);

    // ---- v phase ----
    u16* crv  = aReg;                               // bf16 relu(v), 16 MB
    u16* vt   = tReg;                               // [8,1024,3072] bf16, 48 MB
    u16* vres = aReg;
    cvt_kernel<<<4096, 256, 0, stream>>>(v, crv, 1048576, 1);
    cvt_kernel<<<1536, 256, 0, stream>>>(Wv, cWt, 393216, 0);
    cvt_kernel<<<512, 256, 0, stream>>>(Wvo, cWo, 131072, 0);
    gemm_bt_kernel<<<dim3(24, 64), 256, 0, stream>>>(crv, cWt, bv, gq4v, vt, nullptr,
                                                     8192, 3072, 1024, 1024, 2048);
    attn_kernel<<<dim3(8, 64), 256, 0, stream>>>(vt, v, vres, 1024);
    gemm_bt_kernel<<<dim3(8, 64), 256, 0, stream>>>(vres, cWo, bvo, nullptr, nullptr,
                                                    out, 8192, 1024, 1024, 1024, 0);
}